// Round 5
// baseline (266.189 us; speedup 1.0000x reference)
//
#include <hip/hip_runtime.h>

// SparseMaxPool — R4. KEY FIX: output is FLOAT32 (map2d.dtype == x.dtype ==
// float32; the stub's rule "reference output dtype -> else float*" applies).
// R0-R2 wrote packed bf16 into the fp32 buffer -> deterministic absmax 7.09375
// identical across three mechanically different kernels; R3's inf proved the
// INPUT is fp32. This round: fp32 in, fp32 out, values bit-exact vs reference.
//
// Design (vouched bit-identical to a literal transcription of the Python):
// one wave per (b,d) row; 31-stage maxpool chain via wave shuffles into a
// compact 1104-float LDS array; emit the 64x64 fp32 tile with coalesced 16B
// float4 stores via a 64-entry diagonal->(base,shift) table. Tiny second
// kernel writes the 32 mask copies (1.0f at valid positions).
// Write-BW bound: ~269 MB out, 4 MB in -> ~43 us roofline at 6.3 TB/s.

typedef unsigned int u32;

// 31 pool stages: output length and offset of each stage's values in the
// compact per-row vals[] (vals[0..63] = original x). Stages 15 and 23 are
// k=3,s=2; the rest k=2,s=1.
__device__ __constant__ int SPEC_LEN[31] = {
  63,62,61,60,59,58,57,56,55,54,53,52,51,50,49,
  24,23,22,21,20,19,18,17,
  8,7,6,5,4,3,2,1};
__device__ __constant__ int SPEC_BASE[31] = {
  64,127,189,250,310,369,427,484,540,595,649,702,754,805,855,
  904,928,951,973,994,1014,1033,1051,
  1068,1076,1083,1089,1094,1098,1101,1103};

// Diff table: for d = c - r in [0,63], entry = base | (shift<<16) | 1<<24.
// Valid iff entry != 0 && (r & ((1<<shift)-1)) == 0; value = vals[base + (r>>shift)].
// (t < len is implied by c <= 63.)
#define E(base, sh) ((base) | ((sh) << 16) | (1 << 24))
__device__ __constant__ int DTAB[64] = {
  E(0,0),   E(64,0),  E(127,0), E(189,0), E(250,0), E(310,0), E(369,0), E(427,0),
  E(484,0), E(540,0), E(595,0), E(649,0), E(702,0), E(754,0), E(805,0), E(855,0),
  0,        E(904,1), 0,        E(928,1), 0,        E(951,1), 0,        E(973,1),
  0,        E(994,1), 0,        E(1014,1),0,        E(1033,1),0,        E(1051,1),
  0, 0, 0,  E(1068,2),0, 0, 0,  E(1076,2),0, 0, 0,  E(1083,2),0, 0, 0,  E(1089,2),
  0, 0, 0,  E(1094,2),0, 0, 0,  E(1098,2),0, 0, 0,  E(1101,2),0, 0, 0,  E(1103,2)
};
#undef E

__device__ __forceinline__ float tile_elem(const float* v, const int* dt, int r, int c) {
  const int d = c - r;
  if (d < 0) return 0.f;
  const int e  = dt[d];
  const int sh = (e >> 16) & 0xFF;
  if (e != 0 && ((r & ((1 << sh) - 1)) == 0)) return v[(e & 0xFFFF) + (r >> sh)];
  return 0.f;
}

__global__ void __launch_bounds__(256)
pool_map_kernel(const float* __restrict__ x, float* __restrict__ out) {
  __shared__ float vals[4][1104];   // per-wave compact pooled values
  __shared__ int dtab[64];

  const int tid  = threadIdx.x;
  const int w    = tid >> 6;
  const int lane = tid & 63;
  if (tid < 64) dtab[tid] = DTAB[tid];

  const int row = blockIdx.x * 4 + w;            // (b*D + d) row index
  float cur = x[(size_t)row * 64 + lane];        // fp32 input
  vals[w][lane] = cur;

  // 31-stage pool chain, wave-synchronous. Lanes >= stage length hold garbage
  // but are never read (each stage reads only lanes < its input length).
#pragma unroll
  for (int m = 0; m < 31; ++m) {
    if (m == 15 || m == 23) {                    // k=3, s=2
      float a = __shfl(cur, 2 * lane);
      float b = __shfl(cur, 2 * lane + 1);
      float c = __shfl(cur, 2 * lane + 2);
      cur = fmaxf(fmaxf(a, b), c);
    } else {                                     // k=2, s=1
      cur = fmaxf(cur, __shfl_down(cur, 1));
    }
    if (lane < SPEC_LEN[m]) vals[w][SPEC_BASE[m] + lane] = cur;
  }
  __syncthreads();                               // vals + dtab ready

  // Emit the 64x64 fp32 tile: 16 iters x 64 lanes x 4 floats (16B stores).
  const float* v = vals[w];
  float* orow = out + (size_t)row * 4096;
#pragma unroll
  for (int it = 0; it < 16; ++it) {
    const int f  = it * 256 + lane * 4;          // 4 elems within one tile row
    const int r  = f >> 6;
    const int c0 = f & 63;
    float4 o;
    o.x = tile_elem(v, dtab, r, c0);
    o.y = tile_elem(v, dtab, r, c0 + 1);
    o.z = tile_elem(v, dtab, r, c0 + 2);
    o.w = tile_elem(v, dtab, r, c0 + 3);
    *(float4*)(orow + f) = o;
  }
}

__device__ __forceinline__ float mask_val(int r, int c) {
  const int d = c - r;
  if (d < 0) return 0.f;
  const int e  = DTAB[d];
  const int sh = (e >> 16) & 0xFF;
  return (e != 0 && ((r & ((1 << sh) - 1)) == 0)) ? 1.f : 0.f;
}

__global__ void __launch_bounds__(256)
mask_kernel(float* __restrict__ out, int nvec) {
  const int i = blockIdx.x * 256 + threadIdx.x;  // one float4 per thread
  if (i >= nvec) return;
  const int f  = (i * 4) & 4095;                 // position within the 64x64 mask
  const int r  = f >> 6;
  const int c0 = f & 63;
  float4 o;
  o.x = mask_val(r, c0);
  o.y = mask_val(r, c0 + 1);
  o.z = mask_val(r, c0 + 2);
  o.w = mask_val(r, c0 + 3);
  *(float4*)(out + (size_t)i * 4) = o;
}

extern "C" void kernel_launch(void* const* d_in, const int* in_sizes, int n_in,
                              void* d_out, int out_size, void* d_ws, size_t ws_size,
                              hipStream_t stream) {
  const float* x = (const float*)d_in[0];        // fp32 input
  float* out = (float*)d_out;                    // fp32 output

  const int nx    = in_sizes[0];                 // B*D*64 = 1048576 elements
  const int nrows = nx / 64;                     // B*D    = 16384
  const int B     = out_size / 4096 - nrows;     // = 32 mask copies

  pool_map_kernel<<<dim3(nrows / 4), 256, 0, stream>>>(x, out);

  float* omask = out + (size_t)nrows * 4096;
  const int nvec = (B * 4096) / 4;
  mask_kernel<<<dim3((nvec + 255) / 256), 256, 0, stream>>>(omask, nvec);
}